// Round 12
// baseline (711.149 us; speedup 1.0000x reference)
//
#include <hip/hip_runtime.h>
#include <cstdint>
#include <cstddef>

#define T_TOK 2048
#define DMODEL 1024
#define NEXP 8
#define HID 2048
#define DUMP_ID 4096   // assignment-id for padding rows
#define NBLK 512       // persistent grid: 2 blocks/CU on 256 CUs (capacity >=5)

typedef __bf16 bf16x8 __attribute__((ext_vector_type(8)));
typedef float f32x4 __attribute__((ext_vector_type(4)));
typedef unsigned short u16;
typedef u16 u16x8 __attribute__((ext_vector_type(8)));

__device__ __forceinline__ u16 f2bf(float f) {
    union { float f; unsigned int u; } v; v.f = f;
    unsigned int u = v.u;
    unsigned int r = (u + 0x7FFFu + ((u >> 16) & 1u)) >> 16;  // RNE
    return (u16)r;
}

__device__ __forceinline__ void gl2lds16(const void* g, void* l) {
    __builtin_amdgcn_global_load_lds(
        (const __attribute__((address_space(1))) void*)g,
        (__attribute__((address_space(3))) void*)l,
        16, 0, 0);
}

// ---- manual grid barrier (bar[] zeroed by hipMemsetAsync before launch) ----
// Release fence -> block sync -> lane0 arrive+spin (device-scope atomics)
// -> block sync -> acquire fence.  Same lowering as cooperative grid.sync().
__device__ __forceinline__ void gbar(int* bar, int idx) {
    __threadfence();                         // release: flush our writes
    __syncthreads();
    if (threadIdx.x == 0) {
        atomicAdd(&bar[idx], 1);
        while (atomicAdd(&bar[idx], 0) < NBLK)
            __builtin_amdgcn_s_sleep(8);
    }
    __syncthreads();
    __threadfence();                         // acquire: invalidate for reads
}

// ---------------- GEMM tile (verbatim round-7 body, as device fn) -----------
// MODE 0 (up):   A = xb gathered (row=id>>1, K=1024), B = w_up[e] fp32
//                epilogue: h[e*T+m0+row][n] = bf16( w2[id]*relu(v)^2 )
// MODE 1 (down): A = h contiguous (K=2048), B = w_down[e] fp32
//                epilogue: part[id][n] = v (plain store; ids unique)
template <int MODE>
__device__ void gemm_tile(int tix, const u16* __restrict__ Asrc,
                          const int* __restrict__ list,
                          const int* __restrict__ counts,
                          const float* __restrict__ Ball32,
                          const float* __restrict__ w2,
                          u16* __restrict__ Hout, float* __restrict__ Pout,
                          u16* As, u16* Bs) {
    constexpr int K   = (MODE == 0) ? DMODEL : HID;   // 1024 / 2048
    constexpr int NKT = K / 64;                       // 16 / 32
    constexpr int NTN = ((MODE == 0) ? HID : DMODEL) / 128;  // 16 / 8
    constexpr int LOGNTN = (MODE == 0) ? 4 : 3;

    const int e = tix & 7;                            // expert fixed per block
    const int rest = tix >> 3;
    const int m0 = (rest >> LOGNTN) * 128;
    if (m0 >= counts[e]) return;
    const int n0 = (rest & (NTN - 1)) * 128;

    const int tid = threadIdx.x;
    const int lane = tid & 63;
    const int w = tid >> 6;

    const int* mylist = list + e * T_TOK + m0;
    const float* B32 = Ball32 + (size_t)e * HID * DMODEL;

    const u16* ap[4];
    const float4* bp[4];
    int bwr[4];
    const int c8 = tid & 7;
#pragma unroll
    for (int it = 0; it < 4; ++it) {
        int row = it * 32 + (tid >> 3);
        int gs = c8 ^ (row & 7);
        if (MODE == 0) {
            int id = mylist[row];
            ap[it] = Asrc + (size_t)(id >> 1) * K + gs * 8;   // gathered tokens
        } else {
            ap[it] = Asrc + (size_t)(e * T_TOK + m0 + row) * K + gs * 8;  // contiguous
        }
        bp[it] = (const float4*)(B32 + (size_t)(n0 + row) * K) + c8 * 2;
        bwr[it] = row * 64 + gs * 8;                          // swizzled LDS dst
    }

    const int wm = (w >> 1) * 64;
    const int wn = (w & 1) * 64;
    const int quad = lane >> 4;
    const int lrow = lane & 15;

    f32x4 acc[4][4];
#pragma unroll
    for (int i = 0; i < 4; ++i)
#pragma unroll
        for (int j = 0; j < 4; ++j) acc[i][j] = f32x4{0.f, 0.f, 0.f, 0.f};

    for (int kt = 0; kt < NKT; ++kt) {
#pragma unroll
        for (int it = 0; it < 4; ++it)
            gl2lds16(ap[it] + kt * 64, &As[(it * 256 + w * 64) * 8]);
        float4 bu[4][2];
#pragma unroll
        for (int it = 0; it < 4; ++it) {
            bu[it][0] = bp[it][kt * 16];
            bu[it][1] = bp[it][kt * 16 + 1];
        }
#pragma unroll
        for (int it = 0; it < 4; ++it) {
            u16x8 o;
            o[0] = f2bf(bu[it][0].x); o[1] = f2bf(bu[it][0].y);
            o[2] = f2bf(bu[it][0].z); o[3] = f2bf(bu[it][0].w);
            o[4] = f2bf(bu[it][1].x); o[5] = f2bf(bu[it][1].y);
            o[6] = f2bf(bu[it][1].z); o[7] = f2bf(bu[it][1].w);
            *(u16x8*)&Bs[bwr[it]] = o;
        }
        __syncthreads();  // drain staging
#pragma unroll
        for (int s = 0; s < 2; ++s) {
            const int q = s * 4 + quad;
            bf16x8 af[4], bfr[4];
#pragma unroll
            for (int i = 0; i < 4; ++i) {
                int ra = wm + i * 16 + lrow;
                int rb = wn + i * 16 + lrow;
                af[i]  = *(const bf16x8*)&As[ra * 64 + (q ^ (ra & 7)) * 8];
                bfr[i] = *(const bf16x8*)&Bs[rb * 64 + (q ^ (rb & 7)) * 8];
            }
#pragma unroll
            for (int i = 0; i < 4; ++i)
#pragma unroll
                for (int j = 0; j < 4; ++j)
                    acc[i][j] = __builtin_amdgcn_mfma_f32_16x16x32_bf16(
                        af[i], bfr[j], acc[i][j], 0, 0, 0);
        }
        __syncthreads();  // protect LDS before next stage
    }

    // epilogue: C/D mapping col = lane&15, row = (lane>>4)*4 + reg
#pragma unroll
    for (int i = 0; i < 4; ++i) {
        int mbase = wm + i * 16 + (lane >> 4) * 4;
        int ids[4];
        float ww[4];
#pragma unroll
        for (int r = 0; r < 4; ++r) {
            ids[r] = mylist[mbase + r];
            if (MODE == 0) ww[r] = w2[ids[r]];
        }
#pragma unroll
        for (int j = 0; j < 4; ++j) {
            int n = n0 + wn + j * 16 + (lane & 15);
#pragma unroll
            for (int r = 0; r < 4; ++r) {
                float v = acc[i][j][r];
                if (MODE == 0) {
                    v = (v > 0.f) ? v * v * ww[r] : 0.f;   // pad rows: 0
                    Hout[(size_t)(e * T_TOK + m0 + mbase + r) * HID + n] = f2bf(v);
                } else {
                    if (ids[r] != DUMP_ID)
                        Pout[(size_t)ids[r] * DMODEL + n] = v;
                }
            }
        }
    }
}

// ---------------- fully fused persistent kernel -----------------------------
// phase 0: router + x->bf16 (blocks 0..255) + dump-row zero (block 256)
// phase 1: build lists (blocks 0..7, ballot compaction)
// phase 2: up-GEMM   (2048 tile-slots over 512 blocks; ~1 active tile each)
// phase 3: down-GEMM (1024 tile-slots; ~256 active)
// phase 4: combine   out[t] = part[2t] + part[2t+1]
__global__ __launch_bounds__(256, 2) void moe_fused(
    const float4* __restrict__ x4, const float4* __restrict__ gw4,
    const float* __restrict__ bias,
    u16* __restrict__ xb, unsigned int* __restrict__ selpack,
    float* __restrict__ w2, int* __restrict__ counts, int* __restrict__ list,
    const float* __restrict__ wu32, const float* __restrict__ wd32,
    u16* __restrict__ h, float* __restrict__ part, float* __restrict__ out,
    int* __restrict__ bar) {
    const int b = blockIdx.x;
    const int tid = threadIdx.x;

    __shared__ u16 As[128 * 64];
    __shared__ u16 Bs[128 * 64];
    __shared__ int wsum[4];
    __shared__ int sbase;

    // ---------------- phase 0: router + xb ----------------
    if (b < 256) {
        ushort4* xb4 = (ushort4*)xb;
        const int wv = tid >> 6;
        const int lane = tid & 63;
        const int pair = b * 4 + wv;         // 0..1023
        const int t0 = 2 * pair, t1 = t0 + 1;

        float acc0[NEXP], acc1[NEXP];
#pragma unroll
        for (int e = 0; e < NEXP; ++e) { acc0[e] = 0.f; acc1[e] = 0.f; }
#pragma unroll
        for (int j = 0; j < 4; ++j) {
            int i4 = lane + j * 64;
            float4 a0 = x4[t0 * 256 + i4];
            float4 a1 = x4[t1 * 256 + i4];
            ushort4 s0, s1;
            s0.x = f2bf(a0.x); s0.y = f2bf(a0.y); s0.z = f2bf(a0.z); s0.w = f2bf(a0.w);
            s1.x = f2bf(a1.x); s1.y = f2bf(a1.y); s1.z = f2bf(a1.z); s1.w = f2bf(a1.w);
            xb4[t0 * 256 + i4] = s0;
            xb4[t1 * 256 + i4] = s1;
#pragma unroll
            for (int e = 0; e < NEXP; ++e) {
                float4 g = gw4[e * 256 + i4];
                acc0[e] += a0.x * g.x + a0.y * g.y + a0.z * g.z + a0.w * g.w;
                acc1[e] += a1.x * g.x + a1.y * g.y + a1.z * g.z + a1.w * g.w;
            }
        }
#pragma unroll
        for (int e = 0; e < NEXP; ++e)
            for (int off = 32; off > 0; off >>= 1) {
                acc0[e] += __shfl_xor(acc0[e], off, 64);
                acc1[e] += __shfl_xor(acc1[e], off, 64);
            }
        if (lane == 0) {
#pragma unroll
            for (int tt = 0; tt < 2; ++tt) {
                int t = tt ? t1 : t0;
                float sc[NEXP], bi[NEXP];
#pragma unroll
                for (int e = 0; e < NEXP; ++e) {
                    float a = tt ? acc1[e] : acc0[e];
                    sc[e] = 1.f / (1.f + expf(-a));
                    bi[e] = sc[e] + bias[e];
                }
                int e0 = 0;
                for (int e = 1; e < NEXP; ++e) if (bi[e] > bi[e0]) e0 = e;
                int e1 = -1;
                for (int e = 0; e < NEXP; ++e) {
                    if (e == e0) continue;
                    if (e1 < 0 || bi[e] > bi[e1]) e1 = e;
                }
                selpack[t] = (unsigned int)e0 | ((unsigned int)e1 << 8);
                w2[2 * t]     = sc[e0] * sc[e0];
                w2[2 * t + 1] = sc[e1] * sc[e1];
            }
        }
    } else if (b == 256) {                   // zero xb dump row (row 2048)
        unsigned int* xbdump = (unsigned int*)(xb + (size_t)T_TOK * DMODEL);
        for (int i = tid; i < DMODEL / 2; i += 256) xbdump[i] = 0;
    }
    gbar(bar, 0);

    // ---------------- phase 1: build lists ----------------
    if (b < NEXP) {
        const int e = b;
        const int lane = tid & 63;
        const int wv = tid >> 6;
        if (tid == 0) sbase = 0;
        __syncthreads();
        for (int tb = 0; tb < T_TOK; tb += 256) {
            int t = tb + tid;
            unsigned int sp = selpack[t];
            bool f1 = ((sp >> 8) & 255u) == (unsigned)e;
            bool f = ((sp & 255u) == (unsigned)e) | f1;
            int id = 2 * t + (f1 ? 1 : 0);
            unsigned long long m = __ballot(f);
            int pos = __popcll(m & ((1ull << lane) - 1ull));
            if (lane == 0) wsum[wv] = __popcll(m);
            __syncthreads();
            int woff = 0;
#pragma unroll
            for (int i = 0; i < 4; ++i) if (i < wv) woff += wsum[i];
            int bse = sbase;
            if (f) list[e * T_TOK + bse + woff + pos] = id;
            __syncthreads();
            if (tid == 0) sbase = bse + wsum[0] + wsum[1] + wsum[2] + wsum[3];
        }
        __syncthreads();
        int total = sbase;
        if (tid == 0) counts[e] = total;
        for (int i = total + tid; i < T_TOK; i += 256) list[e * T_TOK + i] = DUMP_ID;
    }
    gbar(bar, 1);

    // ---------------- phase 2: up-GEMM ----------------
    for (int t = b; t < (T_TOK / 128) * (HID / 128) * NEXP; t += NBLK)
        gemm_tile<0>(t, xb, list, counts, wu32, w2, h, nullptr, As, Bs);
    gbar(bar, 2);

    // ---------------- phase 3: down-GEMM ----------------
    for (int t = b; t < (T_TOK / 128) * (DMODEL / 128) * NEXP; t += NBLK)
        gemm_tile<1>(t, h, list, counts, wd32, w2, nullptr, part, As, Bs);
    gbar(bar, 3);

    // ---------------- phase 4: combine ----------------
    {
        const float4* p4 = (const float4*)part;
        float4* o4 = (float4*)out;
        for (int idx = b * 256 + tid; idx < T_TOK * DMODEL / 4; idx += NBLK * 256) {
            int t = idx >> 8;
            int d4 = idx & 255;
            float4 p0 = p4[(size_t)(2 * t) * 256 + d4];
            float4 p1 = p4[(size_t)(2 * t + 1) * 256 + d4];
            float4 o;
            o.x = p0.x + p1.x; o.y = p0.y + p1.y;
            o.z = p0.z + p1.z; o.w = p0.w + p1.w;
            o4[idx] = o;
        }
    }
}

// ---------------------------------------------------------------------------
extern "C" void kernel_launch(void* const* d_in, const int* in_sizes, int n_in,
                              void* d_out, int out_size, void* d_ws, size_t ws_size,
                              hipStream_t stream) {
    const float4* x4  = (const float4*)d_in[0];
    const float4* gw4 = (const float4*)d_in[1];
    const float* wu32 = (const float*)d_in[2];
    const float* wd32 = (const float*)d_in[3];
    const float* bias = (const float*)d_in[4];
    float* out = (float*)d_out;

    // workspace layout (16B aligned chunks)
    char* p = (char*)d_ws;
    int* bar    = (int*)p;                 p += 64;    // 4 barrier slots (+pad)
    int* counts = (int*)p;                 p += 256;
    int* list   = (int*)p;                 p += NEXP * T_TOK * 4;
    float* w2   = (float*)p;               p += 4104 * 4;
    unsigned int* selpack = (unsigned int*)p;  p += T_TOK * 4;
    u16* xb  = (u16*)p;  p += (size_t)(T_TOK + 1) * DMODEL * 2;          // ~4 MB
    u16* h   = (u16*)p;  p += (size_t)NEXP * T_TOK * HID * 2;            // 64 MB
    float* part = (float*)p;  p += (size_t)2 * T_TOK * DMODEL * 4;       // 16 MB

    // 0. zero the barrier slots (graph-ordered before the kernel each replay)
    hipMemsetAsync(bar, 0, 64, stream);

    // 1. fully fused persistent kernel (plain launch, manual grid barrier)
    moe_fused<<<NBLK, 256, 0, stream>>>(
        x4, gw4, bias, xb, selpack, w2, counts, list,
        wu32, wd32, h, part, out, bar);
}